// Round 8
// baseline (206.498 us; speedup 1.0000x reference)
//
#include <hip/hip_runtime.h>

#define NF 512
// 1/sqrt(512)
#define SCALE 0.044194173824159216f

#if defined(__has_builtin)
#  if __has_builtin(__builtin_amdgcn_permlane32_swap)
#    define HAVE_PL32 1
#  else
#    define HAVE_PL32 0
#  endif
#  if __has_builtin(__builtin_amdgcn_permlane16_swap)
#    define HAVE_PL16 1
#  else
#    define HAVE_PL16 0
#  endif
#else
#  define HAVE_PL32 0
#  define HAVE_PL16 0
#endif

typedef unsigned uint2v __attribute__((ext_vector_type(2)));
typedef float f32x4 __attribute__((ext_vector_type(4)));

// DPP cross-lane move: dst[lane] = src[permuted lane].
template<int CTRL>
__device__ __forceinline__ float dppf(float x) {
    const int xi = __float_as_int(x);
    return __int_as_float(__builtin_amdgcn_update_dpp(xi, xi, CTRL, 0xF, 0xF, true));
}

// ds_swizzle xor-mask move (BitMode: (xor<<10)|0x1F).
template<int PAT>
__device__ __forceinline__ float swzf(float x) {
    return __int_as_float(__builtin_amdgcn_ds_swizzle(__float_as_int(x), PAT));
}

#if HAVE_PL16
__device__ __forceinline__ void bfly16(float& a, float& b) {
    uint2v t = __builtin_amdgcn_permlane16_swap(__float_as_uint(a), __float_as_uint(b), false, false);
    const float lo = __uint_as_float(t[0]);
    const float hi = __uint_as_float(t[1]);
    const float s = lo + hi;
    const float d = lo - hi;
    uint2v u = __builtin_amdgcn_permlane16_swap(__float_as_uint(s), __float_as_uint(d), false, false);
    a = __uint_as_float(u[0]);
    b = __uint_as_float(u[1]);
}
#endif

#if HAVE_PL32
__device__ __forceinline__ void bfly32(float& a, float& b) {
    uint2v t = __builtin_amdgcn_permlane32_swap(__float_as_uint(a), __float_as_uint(b), false, false);
    const float lo = __uint_as_float(t[0]);
    const float hi = __uint_as_float(t[1]);
    const float s = lo + hi;
    const float d = lo - hi;
    uint2v u = __builtin_amdgcn_permlane32_swap(__float_as_uint(s), __float_as_uint(d), false, false);
    a = __uint_as_float(u[0]);
    b = __uint_as_float(u[1]);
}
#endif

// Two independent 512-pt WHTs, stages interleaved instruction-by-instruction.
__device__ __forceinline__ void wht512_pair(float a[8], float b[8],
                                            const float sg1, const float sg2,
                                            const float sg4, const float sg8,
                                            const float sg16, const float sg32) {
    (void)sg16; (void)sg32;
    // Intra-lane stages: strides 1,2,4.
#pragma unroll
    for (int s = 1; s < 8; s <<= 1) {
#pragma unroll
        for (int j = 0; j < 8; ++j) {
            if (!(j & s)) {
                const float ua = a[j], wa = a[j | s];
                const float ub = b[j], wb = b[j | s];
                a[j] = ua + wa; a[j | s] = ua - wa;
                b[j] = ub + wb; b[j | s] = ub - wb;
            }
        }
    }
    // lane-xor 1: DPP quad_perm [1,0,3,2]
#pragma unroll
    for (int j = 0; j < 8; ++j) {
        const float pa = dppf<0xB1>(a[j]);
        const float pb = dppf<0xB1>(b[j]);
        a[j] = fmaf(sg1, a[j], pa);
        b[j] = fmaf(sg1, b[j], pb);
    }
    // lane-xor 2: DPP quad_perm [2,3,0,1]
#pragma unroll
    for (int j = 0; j < 8; ++j) {
        const float pa = dppf<0x4E>(a[j]);
        const float pb = dppf<0x4E>(b[j]);
        a[j] = fmaf(sg2, a[j], pa);
        b[j] = fmaf(sg2, b[j], pb);
    }
    // lane-xor 4: ds_swizzle xor-4
#pragma unroll
    for (int j = 0; j < 8; ++j) {
        const float pa = swzf<0x101F>(a[j]);
        const float pb = swzf<0x101F>(b[j]);
        a[j] = fmaf(sg4, a[j], pa);
        b[j] = fmaf(sg4, b[j], pb);
    }
    // lane-xor 8: DPP row_ror:8
#pragma unroll
    for (int j = 0; j < 8; ++j) {
        const float pa = dppf<0x128>(a[j]);
        const float pb = dppf<0x128>(b[j]);
        a[j] = fmaf(sg8, a[j], pa);
        b[j] = fmaf(sg8, b[j], pb);
    }
    // lane-xor 16
#if HAVE_PL16
#pragma unroll
    for (int j = 0; j < 8; j += 2) { bfly16(a[j], a[j + 1]); bfly16(b[j], b[j + 1]); }
#else
#pragma unroll
    for (int j = 0; j < 8; ++j) {
        const float pa = swzf<0x401F>(a[j]);
        const float pb = swzf<0x401F>(b[j]);
        a[j] = fmaf(sg16, a[j], pa);
        b[j] = fmaf(sg16, b[j], pb);
    }
#endif
    // lane-xor 32
#if HAVE_PL32
#pragma unroll
    for (int j = 0; j < 8; j += 2) { bfly32(a[j], a[j + 1]); bfly32(b[j], b[j + 1]); }
#else
#pragma unroll
    for (int j = 0; j < 8; ++j) {
        const float pa = __shfl_xor(a[j], 32, 64);
        const float pb = __shfl_xor(b[j], 32, 64);
        a[j] = fmaf(sg32, a[j], pa);
        b[j] = fmaf(sg32, b[j], pb);
    }
#endif
}

__global__ __launch_bounds__(256, 4)
void wht512_soft_kernel(const float* __restrict__ x,
                        const float* __restrict__ gate,
                        const float* __restrict__ thr,
                        float* __restrict__ out,
                        const int nrows) {
    const int lane = threadIdx.x & 63;
    const int wave = blockIdx.x * (blockDim.x >> 6) + (threadIdx.x >> 6);
    const int nwaves = gridDim.x * (blockDim.x >> 6);
    const int npairs = nrows >> 1;  // nrows is even (262144)

    const float sg1  = (lane & 1)  ? -1.0f : 1.0f;
    const float sg2  = (lane & 2)  ? -1.0f : 1.0f;
    const float sg4  = (lane & 4)  ? -1.0f : 1.0f;
    const float sg8  = (lane & 8)  ? -1.0f : 1.0f;
    const float sg16 = (lane & 16) ? -1.0f : 1.0f;
    const float sg32 = (lane & 32) ? -1.0f : 1.0f;

    // Per-lane gate (first 1/sqrt(n) folded in) and threshold, features lane*8+j.
    float vg[8], tg[8];
    {
        const f32x4 a = ((const f32x4*)gate)[lane * 2];
        const f32x4 b = ((const f32x4*)gate)[lane * 2 + 1];
        vg[0] = a.x * SCALE; vg[1] = a.y * SCALE; vg[2] = a.z * SCALE; vg[3] = a.w * SCALE;
        vg[4] = b.x * SCALE; vg[5] = b.y * SCALE; vg[6] = b.z * SCALE; vg[7] = b.w * SCALE;
        const f32x4 c = ((const f32x4*)thr)[lane * 2];
        const f32x4 d = ((const f32x4*)thr)[lane * 2 + 1];
        tg[0] = c.x; tg[1] = c.y; tg[2] = c.z; tg[3] = c.w;
        tg[4] = d.x; tg[5] = d.y; tg[6] = d.z; tg[7] = d.w;
    }

    // Software pipeline, depth 2: c = current, p1 = +1 iteration, p2 = +2.
    int pr = wave;
    f32x4 c0a, c0b, c1a, c1b;       // current pair
    f32x4 p0a, p0b, p1a, p1b;       // next pair (in flight)
    if (pr < npairs) {
        const f32x4* x0 = (const f32x4*)(x + (size_t)(2 * pr) * NF);
        c0a = x0[lane * 2];
        c0b = x0[lane * 2 + 1];
        c1a = x0[128 + lane * 2];
        c1b = x0[128 + lane * 2 + 1];
    }
    if (pr + nwaves < npairs) {
        const f32x4* x1 = (const f32x4*)(x + (size_t)(2 * (pr + nwaves)) * NF);
        p0a = x1[lane * 2];
        p0b = x1[lane * 2 + 1];
        p1a = x1[128 + lane * 2];
        p1b = x1[128 + lane * 2 + 1];
    }

    for (; pr < npairs; pr += nwaves) {
        // Issue loads two iterations ahead.
        const int ppr = pr + 2 * nwaves;
        f32x4 q0a = c0a, q0b = c0b, q1a = c1a, q1b = c1b;  // placeholder defaults
        if (ppr < npairs) {
            const f32x4* xq = (const f32x4*)(x + (size_t)(2 * ppr) * NF);
            q0a = xq[lane * 2];
            q0b = xq[lane * 2 + 1];
            q1a = xq[128 + lane * 2];
            q1b = xq[128 + lane * 2 + 1];
        }

        float r0[8] = {c0a.x, c0a.y, c0a.z, c0a.w, c0b.x, c0b.y, c0b.z, c0b.w};
        float r1[8] = {c1a.x, c1a.y, c1a.z, c1a.w, c1b.x, c1b.y, c1b.z, c1b.w};

        // f1 (unscaled): H x — both rows interleaved
        wht512_pair(r0, r1, sg1, sg2, sg4, sg8, sg16, sg32);

        // f2 = v * (f1/sqrt(n));  f3 = sign(f2)*relu(|f2|-T)
#pragma unroll
        for (int j = 0; j < 8; ++j) {
            const float f0 = r0[j] * vg[j];
            const float f1 = r1[j] * vg[j];
            const float m0 = fabsf(f0) - tg[j];
            const float m1 = fabsf(f1) - tg[j];
            r0[j] = (m0 > 0.0f) ? copysignf(m0, f0) : 0.0f;
            r1[j] = (m1 > 0.0f) ? copysignf(m1, f1) : 0.0f;
        }

        // f4 (unscaled): H f3
        wht512_pair(r0, r1, sg1, sg2, sg4, sg8, sg16, sg32);

        // out = f4/sqrt(n) + x
        f32x4 o0a, o0b, o1a, o1b;
        o0a.x = fmaf(r0[0], SCALE, c0a.x); o0a.y = fmaf(r0[1], SCALE, c0a.y);
        o0a.z = fmaf(r0[2], SCALE, c0a.z); o0a.w = fmaf(r0[3], SCALE, c0a.w);
        o0b.x = fmaf(r0[4], SCALE, c0b.x); o0b.y = fmaf(r0[5], SCALE, c0b.y);
        o0b.z = fmaf(r0[6], SCALE, c0b.z); o0b.w = fmaf(r0[7], SCALE, c0b.w);
        o1a.x = fmaf(r1[0], SCALE, c1a.x); o1a.y = fmaf(r1[1], SCALE, c1a.y);
        o1a.z = fmaf(r1[2], SCALE, c1a.z); o1a.w = fmaf(r1[3], SCALE, c1a.w);
        o1b.x = fmaf(r1[4], SCALE, c1b.x); o1b.y = fmaf(r1[5], SCALE, c1b.y);
        o1b.z = fmaf(r1[6], SCALE, c1b.z); o1b.w = fmaf(r1[7], SCALE, c1b.w);

        f32x4* orow = (f32x4*)(out + (size_t)(2 * pr) * NF);
        orow[lane * 2]           = o0a;
        orow[lane * 2 + 1]       = o0b;
        orow[128 + lane * 2]     = o1a;
        orow[128 + lane * 2 + 1] = o1b;

        // Rotate pipeline.
        c0a = p0a; c0b = p0b; c1a = p1a; c1b = p1b;
        p0a = q0a; p0b = q0b; p1a = q1a; p1b = q1b;
    }
}

extern "C" void kernel_launch(void* const* d_in, const int* in_sizes, int n_in,
                              void* d_out, int out_size, void* d_ws, size_t ws_size,
                              hipStream_t stream) {
    const float* x = (const float*)d_in[0];
    const float* v = (const float*)d_in[1];
    const float* T = (const float*)d_in[2];
    float* out = (float*)d_out;

    const int nrows = in_sizes[0] / NF;  // 64*4096 = 262144

    dim3 block(256);
    dim3 grid(4096);  // 16384 waves; 131072 pairs -> 8 pairs/wave grid-stride
    hipLaunchKernelGGL(wht512_soft_kernel, grid, block, 0, stream, x, v, T, out, nrows);
}

// Round 9
// 202.905 us; speedup vs baseline: 1.0177x; 1.0177x over previous
//
#include <hip/hip_runtime.h>

#define NF 512
// 1/sqrt(512)
#define SCALE 0.044194173824159216f

#if defined(__has_builtin)
#  if __has_builtin(__builtin_amdgcn_permlane32_swap)
#    define HAVE_PL32 1
#  else
#    define HAVE_PL32 0
#  endif
#  if __has_builtin(__builtin_amdgcn_permlane16_swap)
#    define HAVE_PL16 1
#  else
#    define HAVE_PL16 0
#  endif
#else
#  define HAVE_PL32 0
#  define HAVE_PL16 0
#endif

typedef unsigned uint2v __attribute__((ext_vector_type(2)));
typedef float f32x4 __attribute__((ext_vector_type(4)));

// Element mapping (per row): register slot (h,j) of lane l holds feature
// e = 256*h + 4*l + j  (h = slot>>2, j = slot&3).
// Intra-lane butterflies over slots realize feature strides 1,2 (j bits) and
// 256 (h bit); lane-xor butterflies 1..32 realize strides 4..128. Hadamard
// stages commute, so this computes the same full WHT as natural order.
// Both vector loads per row are dense 64x16B = 1KB contiguous.

// DPP cross-lane move: dst[lane] = src[permuted lane].
template<int CTRL>
__device__ __forceinline__ float dppf(float x) {
    const int xi = __float_as_int(x);
    return __int_as_float(__builtin_amdgcn_update_dpp(xi, xi, CTRL, 0xF, 0xF, true));
}

// ds_swizzle xor-mask move (BitMode: (xor<<10)|0x1F).
template<int PAT>
__device__ __forceinline__ float swzf(float x) {
    return __int_as_float(__builtin_amdgcn_ds_swizzle(__float_as_int(x), PAT));
}

#if HAVE_PL16
__device__ __forceinline__ void bfly16(float& a, float& b) {
    uint2v t = __builtin_amdgcn_permlane16_swap(__float_as_uint(a), __float_as_uint(b), false, false);
    const float lo = __uint_as_float(t[0]);
    const float hi = __uint_as_float(t[1]);
    const float s = lo + hi;
    const float d = lo - hi;
    uint2v u = __builtin_amdgcn_permlane16_swap(__float_as_uint(s), __float_as_uint(d), false, false);
    a = __uint_as_float(u[0]);
    b = __uint_as_float(u[1]);
}
#endif

#if HAVE_PL32
__device__ __forceinline__ void bfly32(float& a, float& b) {
    uint2v t = __builtin_amdgcn_permlane32_swap(__float_as_uint(a), __float_as_uint(b), false, false);
    const float lo = __uint_as_float(t[0]);
    const float hi = __uint_as_float(t[1]);
    const float s = lo + hi;
    const float d = lo - hi;
    uint2v u = __builtin_amdgcn_permlane32_swap(__float_as_uint(s), __float_as_uint(d), false, false);
    a = __uint_as_float(u[0]);
    b = __uint_as_float(u[1]);
}
#endif

// Two independent 512-pt WHTs, stages interleaved instruction-by-instruction.
__device__ __forceinline__ void wht512_pair(float a[8], float b[8],
                                            const float sg1, const float sg2,
                                            const float sg4, const float sg8,
                                            const float sg16, const float sg32) {
    (void)sg16; (void)sg32;
    // Intra-lane stages over slot strides 1,2,4 (= feature strides 1,2,256).
#pragma unroll
    for (int s = 1; s < 8; s <<= 1) {
#pragma unroll
        for (int j = 0; j < 8; ++j) {
            if (!(j & s)) {
                const float ua = a[j], wa = a[j | s];
                const float ub = b[j], wb = b[j | s];
                a[j] = ua + wa; a[j | s] = ua - wa;
                b[j] = ub + wb; b[j | s] = ub - wb;
            }
        }
    }
    // lane-xor 1 (feature stride 4): DPP quad_perm [1,0,3,2]
#pragma unroll
    for (int j = 0; j < 8; ++j) {
        const float pa = dppf<0xB1>(a[j]);
        const float pb = dppf<0xB1>(b[j]);
        a[j] = fmaf(sg1, a[j], pa);
        b[j] = fmaf(sg1, b[j], pb);
    }
    // lane-xor 2: DPP quad_perm [2,3,0,1]
#pragma unroll
    for (int j = 0; j < 8; ++j) {
        const float pa = dppf<0x4E>(a[j]);
        const float pb = dppf<0x4E>(b[j]);
        a[j] = fmaf(sg2, a[j], pa);
        b[j] = fmaf(sg2, b[j], pb);
    }
    // lane-xor 4: ds_swizzle xor-4
#pragma unroll
    for (int j = 0; j < 8; ++j) {
        const float pa = swzf<0x101F>(a[j]);
        const float pb = swzf<0x101F>(b[j]);
        a[j] = fmaf(sg4, a[j], pa);
        b[j] = fmaf(sg4, b[j], pb);
    }
    // lane-xor 8: DPP row_ror:8
#pragma unroll
    for (int j = 0; j < 8; ++j) {
        const float pa = dppf<0x128>(a[j]);
        const float pb = dppf<0x128>(b[j]);
        a[j] = fmaf(sg8, a[j], pa);
        b[j] = fmaf(sg8, b[j], pb);
    }
    // lane-xor 16
#if HAVE_PL16
#pragma unroll
    for (int j = 0; j < 8; j += 2) { bfly16(a[j], a[j + 1]); bfly16(b[j], b[j + 1]); }
#else
#pragma unroll
    for (int j = 0; j < 8; ++j) {
        const float pa = swzf<0x401F>(a[j]);
        const float pb = swzf<0x401F>(b[j]);
        a[j] = fmaf(sg16, a[j], pa);
        b[j] = fmaf(sg16, b[j], pb);
    }
#endif
    // lane-xor 32
#if HAVE_PL32
#pragma unroll
    for (int j = 0; j < 8; j += 2) { bfly32(a[j], a[j + 1]); bfly32(b[j], b[j + 1]); }
#else
#pragma unroll
    for (int j = 0; j < 8; ++j) {
        const float pa = __shfl_xor(a[j], 32, 64);
        const float pb = __shfl_xor(b[j], 32, 64);
        a[j] = fmaf(sg32, a[j], pa);
        b[j] = fmaf(sg32, b[j], pb);
    }
#endif
}

__global__ __launch_bounds__(256, 4)
void wht512_soft_kernel(const float* __restrict__ x,
                        const float* __restrict__ gate,
                        const float* __restrict__ thr,
                        float* __restrict__ out,
                        const int nrows) {
    const int lane = threadIdx.x & 63;
    const int wave = blockIdx.x * (blockDim.x >> 6) + (threadIdx.x >> 6);
    const int nwaves = gridDim.x * (blockDim.x >> 6);
    const int npairs = nrows >> 1;  // nrows is even (262144)

    const float sg1  = (lane & 1)  ? -1.0f : 1.0f;
    const float sg2  = (lane & 2)  ? -1.0f : 1.0f;
    const float sg4  = (lane & 4)  ? -1.0f : 1.0f;
    const float sg8  = (lane & 8)  ? -1.0f : 1.0f;
    const float sg16 = (lane & 16) ? -1.0f : 1.0f;
    const float sg32 = (lane & 32) ? -1.0f : 1.0f;

    // Per-lane gate (first 1/sqrt(n) folded in) and threshold.
    // Slot h*4+j holds feature 256h+4l+j -> dense f32x4 at [lane] and [64+lane].
    float vg[8], tg[8];
    {
        const f32x4 a = ((const f32x4*)gate)[lane];
        const f32x4 b = ((const f32x4*)gate)[64 + lane];
        vg[0] = a.x * SCALE; vg[1] = a.y * SCALE; vg[2] = a.z * SCALE; vg[3] = a.w * SCALE;
        vg[4] = b.x * SCALE; vg[5] = b.y * SCALE; vg[6] = b.z * SCALE; vg[7] = b.w * SCALE;
        const f32x4 c = ((const f32x4*)thr)[lane];
        const f32x4 d = ((const f32x4*)thr)[64 + lane];
        tg[0] = c.x; tg[1] = c.y; tg[2] = c.z; tg[3] = c.w;
        tg[4] = d.x; tg[5] = d.y; tg[6] = d.z; tg[7] = d.w;
    }

    int pr = wave;
    f32x4 c0a, c0b, c1a, c1b;
    if (pr < npairs) {
        const f32x4* x0 = (const f32x4*)(x + (size_t)(2 * pr) * NF);
        c0a = x0[lane];            // row0 features 4l..4l+3      (bytes 0..1023 dense)
        c0b = x0[64 + lane];       // row0 features 256+4l..      (bytes 1024..2047 dense)
        c1a = x0[128 + lane];      // row1 first half
        c1b = x0[192 + lane];      // row1 second half
    }

    for (; pr < npairs; pr += nwaves) {
        // Prefetch next pair before computing the current one.
        const int npr = pr + nwaves;
        f32x4 n0a = c0a, n0b = c0b, n1a = c1a, n1b = c1b;
        if (npr < npairs) {
            const f32x4* xn = (const f32x4*)(x + (size_t)(2 * npr) * NF);
            n0a = xn[lane];
            n0b = xn[64 + lane];
            n1a = xn[128 + lane];
            n1b = xn[192 + lane];
        }

        float r0[8] = {c0a.x, c0a.y, c0a.z, c0a.w, c0b.x, c0b.y, c0b.z, c0b.w};
        float r1[8] = {c1a.x, c1a.y, c1a.z, c1a.w, c1b.x, c1b.y, c1b.z, c1b.w};

        // f1 (unscaled): H x — both rows interleaved
        wht512_pair(r0, r1, sg1, sg2, sg4, sg8, sg16, sg32);

        // f2 = v * (f1/sqrt(n));  f3 = sign(f2)*relu(|f2|-T)
#pragma unroll
        for (int j = 0; j < 8; ++j) {
            const float f0 = r0[j] * vg[j];
            const float f1 = r1[j] * vg[j];
            const float m0 = fabsf(f0) - tg[j];
            const float m1 = fabsf(f1) - tg[j];
            r0[j] = (m0 > 0.0f) ? copysignf(m0, f0) : 0.0f;
            r1[j] = (m1 > 0.0f) ? copysignf(m1, f1) : 0.0f;
        }

        // f4 (unscaled): H f3
        wht512_pair(r0, r1, sg1, sg2, sg4, sg8, sg16, sg32);

        // out = f4/sqrt(n) + x
        f32x4 o0a, o0b, o1a, o1b;
        o0a.x = fmaf(r0[0], SCALE, c0a.x); o0a.y = fmaf(r0[1], SCALE, c0a.y);
        o0a.z = fmaf(r0[2], SCALE, c0a.z); o0a.w = fmaf(r0[3], SCALE, c0a.w);
        o0b.x = fmaf(r0[4], SCALE, c0b.x); o0b.y = fmaf(r0[5], SCALE, c0b.y);
        o0b.z = fmaf(r0[6], SCALE, c0b.z); o0b.w = fmaf(r0[7], SCALE, c0b.w);
        o1a.x = fmaf(r1[0], SCALE, c1a.x); o1a.y = fmaf(r1[1], SCALE, c1a.y);
        o1a.z = fmaf(r1[2], SCALE, c1a.z); o1a.w = fmaf(r1[3], SCALE, c1a.w);
        o1b.x = fmaf(r1[4], SCALE, c1b.x); o1b.y = fmaf(r1[5], SCALE, c1b.y);
        o1b.z = fmaf(r1[6], SCALE, c1b.z); o1b.w = fmaf(r1[7], SCALE, c1b.w);

        f32x4* orow = (f32x4*)(out + (size_t)(2 * pr) * NF);
        orow[lane]        = o0a;
        orow[64 + lane]   = o0b;
        orow[128 + lane]  = o1a;
        orow[192 + lane]  = o1b;

        c0a = n0a; c0b = n0b; c1a = n1a; c1b = n1b;
    }
}

extern "C" void kernel_launch(void* const* d_in, const int* in_sizes, int n_in,
                              void* d_out, int out_size, void* d_ws, size_t ws_size,
                              hipStream_t stream) {
    const float* x = (const float*)d_in[0];
    const float* v = (const float*)d_in[1];
    const float* T = (const float*)d_in[2];
    float* out = (float*)d_out;

    const int nrows = in_sizes[0] / NF;  // 64*4096 = 262144

    dim3 block(256);
    dim3 grid(4096);  // 16384 waves; 131072 pairs -> 8 pairs/wave grid-stride
    hipLaunchKernelGGL(wht512_soft_kernel, grid, block, 0, stream, x, v, T, out, nrows);
}